// Round 10
// baseline (199.461 us; speedup 1.0000x reference)
//
#include <hip/hip_runtime.h>
#include <hip/hip_bf16.h>
#include <math.h>

#define N_ROWS 4096
#define D 512
#define TWO_N 8192
#define TILE 128
#define NKT 16               /* 512 / 32 K-tiles */
#define NJB 64               /* 8192 / 128 column blocks */
#define NPAIRS 2080          /* 64*65/2 upper-tri blocks */
#define INV_T 5.0f

typedef __attribute__((ext_vector_type(8))) __bf16 bf16x8;
typedef __attribute__((ext_vector_type(8))) unsigned short u16x8;
typedef __attribute__((ext_vector_type(4))) float f32x4;
#define AS1 __attribute__((address_space(1)))
#define AS3 __attribute__((address_space(3)))

// ---------------- block reduction helper (broadcasts result) ----------------
template<int K>
__device__ inline void block_reduce_bcast(float (&v)[K]) {
  __shared__ float red[4][K];
  const int t = threadIdx.x;
  #pragma unroll
  for (int off = 32; off; off >>= 1)
    #pragma unroll
    for (int i = 0; i < K; ++i) v[i] += __shfl_xor(v[i], off, 64);
  __syncthreads();
  if ((t & 63) == 0)
    #pragma unroll
    for (int i = 0; i < K; ++i) red[t >> 6][i] = v[i];
  __syncthreads();
  #pragma unroll
  for (int i = 0; i < K; ++i) v[i] = red[0][i] + red[1][i] + red[2][i] + red[3][i];
}

// ---------------- kernel 1: wave-per-row normalize (no LDS, shfl-only) -----
__global__ __launch_bounds__(256) void normalize_kernel(
    const float* __restrict__ ei_, const float* __restrict__ ej_,
    const float* __restrict__ ek_,
    __hip_bfloat16* __restrict__ reps, float* __restrict__ diagexp,
    float* __restrict__ pos_ij, float* __restrict__ exp_ik)
{
  const int t = threadIdx.x;
  const int l = t & 63;
  const int n = blockIdx.x * 4 + (t >> 6);
  const long base = (long)n * D + l * 8;

  float ai[8], aj[8], ak[8];
  #pragma unroll
  for (int h = 0; h < 2; ++h) {
    const float4 vi = *reinterpret_cast<const float4*>(ei_ + base + h * 4);
    const float4 vj = *reinterpret_cast<const float4*>(ej_ + base + h * 4);
    const float4 vk = *reinterpret_cast<const float4*>(ek_ + base + h * 4);
    ai[h*4+0]=vi.x; ai[h*4+1]=vi.y; ai[h*4+2]=vi.z; ai[h*4+3]=vi.w;
    aj[h*4+0]=vj.x; aj[h*4+1]=vj.y; aj[h*4+2]=vj.z; aj[h*4+3]=vj.w;
    ak[h*4+0]=vk.x; ak[h*4+1]=vk.y; ak[h*4+2]=vk.z; ak[h*4+3]=vk.w;
  }

  float v[5] = {0.f, 0.f, 0.f, 0.f, 0.f};
  #pragma unroll
  for (int j = 0; j < 8; ++j) {
    v[0] += ai[j] * ai[j];
    v[1] += aj[j] * aj[j];
    v[2] += ak[j] * ak[j];
    v[3] += ai[j] * aj[j];
    v[4] += ak[j] * ai[j];
  }
  #pragma unroll
  for (int off = 32; off; off >>= 1)
    #pragma unroll
    for (int i = 0; i < 5; ++i) v[i] += __shfl_xor(v[i], off, 64);

  const float ni = fmaxf(sqrtf(v[0]), 1e-12f);
  const float nj = fmaxf(sqrtf(v[1]), 1e-12f);
  const float nk = fmaxf(sqrtf(v[2]), 1e-12f);
  const float invi = 1.0f / ni, invj = 1.0f / nj;

  u16x8 ui, uj;
  float q[2] = {0.f, 0.f};
  #pragma unroll
  for (int j = 0; j < 8; ++j) {
    const __hip_bfloat16 hi = __float2bfloat16(ai[j] * invi);
    const __hip_bfloat16 hj = __float2bfloat16(aj[j] * invj);
    ui[j] = *reinterpret_cast<const unsigned short*>(&hi);
    uj[j] = *reinterpret_cast<const unsigned short*>(&hj);
    const float fi = __bfloat162float(hi), fj = __bfloat162float(hj);
    q[0] += fi * fi;
    q[1] += fj * fj;
  }
  *reinterpret_cast<u16x8*>(reps + base) = ui;
  *reinterpret_cast<u16x8*>(reps + (long)N_ROWS * D + base) = uj;

  #pragma unroll
  for (int off = 32; off; off >>= 1)
    #pragma unroll
    for (int i = 0; i < 2; ++i) q[i] += __shfl_xor(q[i], off, 64);

  if (l == 0) {
    diagexp[n]          = __expf(INV_T * q[0]);
    diagexp[N_ROWS + n] = __expf(INV_T * q[1]);
    pos_ij[n] = v[3] / (ni * nj);
    exp_ik[n] = __expf(INV_T * v[4] / (nk * ni));
  }
}

// ---------------- kernel 2: reduce the two scalars --------------------------
__global__ __launch_bounds__(256) void scalar_kernel(
    const float* __restrict__ pos_ij, const float* __restrict__ exp_ik,
    float* __restrict__ scalars)
{
  const int t = threadIdx.x;
  float v[2] = {0.f, 0.f};
  for (int i = t; i < N_ROWS; i += 256) { v[0] += pos_ij[i]; v[1] += exp_ik[i]; }
  block_reduce_bcast<2>(v);
  if (t == 0) { scalars[0] = v[0]; scalars[1] = v[1]; }
}

// ---------------- kernel 3: 128^2 BK=32 dbuf, EXACTLY 32KB LDS -------------
// 5 blocks/CU (5 x 32768 = 163840 = full LDS pool), 20 waves/CU: cross-block
// TLP absorbs the per-K-tile syncthreads drain (R8 schedule, proven).
// Epilogue rowbuf/colbuf REUSE the staging buffers (dead after final barrier).
// Layout per buffer: [128 rows][4 slots x 16B]; slot swizzle ^((row>>1)&3);
// inverse swizzle on global source (both-sides rule).
__device__ __forceinline__ void stage_tile(
    const __hip_bfloat16* __restrict__ reps, char* region,
    long R0, int kt, int p, int t)
{
  #pragma unroll
  for (int s = 0; s < 2; ++s) {
    const int cc = s * 256 + t;          // chunk 0..511
    const int row = cc >> 2, slot = cc & 3;
    const int sl = slot ^ ((row >> 1) & 3);
    const __hip_bfloat16* g = reps + (R0 + row) * D + kt * 32 + sl * 8;
    __builtin_amdgcn_global_load_lds((const AS1 void*)g,
        (AS3 void*)(region + p * 8192 + cc * 16), 16, 0, 0);
  }
}

__global__ __launch_bounds__(256, 5) void gemm_expsum_kernel(
    const __hip_bfloat16* __restrict__ reps, float* __restrict__ S_partial)
{
  __shared__ __align__(16) char smem[32768];
  char* Ar = smem;
  char* Br = smem + 16384;

  const int t = threadIdx.x;
  const int l = t & 63;
  const int w = t >> 6;          // wave 0..3
  const int wr = w >> 1, wc = w & 1;
  const int s4 = l >> 4;

  // XCD-aware bijective swizzle (2080 = 8*260), then triangular decode I<=J
  const int wg = (blockIdx.x & 7) * 260 + (blockIdx.x >> 3);
  int k = wg, I = 0;
  while (k >= NJB - I) { k -= NJB - I; ++I; }
  const int J = I + k;
  const long rI = (long)I * TILE;
  const long cJ = (long)J * TILE;

  // fragment byte offsets (buffer term added at read): row*64 + swizzled slot
  const int swz16 = ((s4 ^ ((l >> 1) & 3)) << 4);
  int a_off[4], b_off[4];
  #pragma unroll
  for (int mi = 0; mi < 4; ++mi)
    a_off[mi] = (wr * 64 + mi * 16 + (l & 15)) * 64 + swz16;
  #pragma unroll
  for (int ni = 0; ni < 4; ++ni)
    b_off[ni] = (wc * 64 + ni * 16 + (l & 15)) * 64 + swz16;

  f32x4 acc[4][4];
  #pragma unroll
  for (int a = 0; a < 4; ++a)
    #pragma unroll
    for (int b = 0; b < 4; ++b) { f32x4 z = {0.f, 0.f, 0.f, 0.f}; acc[a][b] = z; }

  // prologue: stage tile0 into buf0, wait (syncthreads drains vmcnt)
  stage_tile(reps, Ar, rI, 0, 0, t);
  stage_tile(reps, Br, cJ, 0, 0, t);
  __syncthreads();

  for (int kt = 0; kt < NKT; ++kt) {
    const int p = kt & 1;
    if (kt < NKT - 1) {                  // issue next tile BEFORE compute
      stage_tile(reps, Ar, rI, kt + 1, p ^ 1, t);
      stage_tile(reps, Br, cJ, kt + 1, p ^ 1, t);
    }
    bf16x8 av[4], bv[4];
    #pragma unroll
    for (int mi = 0; mi < 4; ++mi)
      av[mi] = *reinterpret_cast<const bf16x8*>(Ar + p * 8192 + a_off[mi]);
    #pragma unroll
    for (int ni = 0; ni < 4; ++ni)
      bv[ni] = *reinterpret_cast<const bf16x8*>(Br + p * 8192 + b_off[ni]);
    __builtin_amdgcn_s_setprio(1);
    #pragma unroll
    for (int mi = 0; mi < 4; ++mi)
      #pragma unroll
      for (int ni = 0; ni < 4; ++ni)
        acc[mi][ni] = __builtin_amdgcn_mfma_f32_16x16x32_bf16(
            av[mi], bv[ni], acc[mi][ni], 0, 0, 0);
    __builtin_amdgcn_s_setprio(0);
    __syncthreads();   // drains vmcnt(0): next tile landed; all done reading p
  }
  // K-loop's final barrier: all waves' ds_reads retired -> smem reusable.
  float* rowbuf = (float*)smem;              // [2][128]
  float* colbuf = (float*)(smem + 1024);     // [2][128]

  // epilogue: e = exp(5*sim); row-sums (rows of I) and col-sums (symmetry)
  float rsum[4][4], csum[4];
  #pragma unroll
  for (int mi = 0; mi < 4; ++mi)
    #pragma unroll
    for (int j = 0; j < 4; ++j) rsum[mi][j] = 0.f;
  #pragma unroll
  for (int ni = 0; ni < 4; ++ni) csum[ni] = 0.f;

  #pragma unroll
  for (int mi = 0; mi < 4; ++mi)
    #pragma unroll
    for (int ni = 0; ni < 4; ++ni)
      #pragma unroll
      for (int j = 0; j < 4; ++j) {
        const float e = __expf(INV_T * acc[mi][ni][j]);
        rsum[mi][j] += e;
        csum[ni]    += e;
      }

  #pragma unroll
  for (int mi = 0; mi < 4; ++mi) {
    #pragma unroll
    for (int off = 1; off < 16; off <<= 1)
      #pragma unroll
      for (int j = 0; j < 4; ++j) rsum[mi][j] += __shfl_xor(rsum[mi][j], off, 64);
    if ((l & 15) == 0) {
      const int rloc = wr * 64 + mi * 16 + s4 * 4;
      #pragma unroll
      for (int j = 0; j < 4; ++j) rowbuf[wc * TILE + rloc + j] = rsum[mi][j];
    }
  }
  #pragma unroll
  for (int off = 16; off < 64; off <<= 1)
    #pragma unroll
    for (int ni = 0; ni < 4; ++ni) csum[ni] += __shfl_xor(csum[ni], off, 64);
  if (l < 16) {
    #pragma unroll
    for (int ni = 0; ni < 4; ++ni)
      colbuf[wr * TILE + wc * 64 + ni * 16 + l] = csum[ni];
  }
  __syncthreads();

  if (t < TILE) {
    S_partial[(long)J * TWO_N + rI + t] = rowbuf[t] + rowbuf[TILE + t];
  } else if (I != J) {
    const int c = t - TILE;
    S_partial[(long)I * TWO_N + cJ + c] = colbuf[c] + colbuf[TILE + c];
  }
}

// ---------------- kernel 4: per-row log(denominator), block partials -------
__global__ __launch_bounds__(256) void rowlog_kernel(
    const float* __restrict__ S_partial, const float* __restrict__ diagexp,
    const float* __restrict__ scalars, float* __restrict__ blockpart)
{
  const int t = threadIdx.x;
  const int r = blockIdx.x * 256 + t;
  float s = 0.f;
  #pragma unroll 8
  for (int Jb = 0; Jb < NJB; ++Jb) s += S_partial[(long)Jb * TWO_N + r];
  const float denom_fu = 2.0f * scalars[1];
  float v[1];
  v[0] = logf(s - diagexp[r] + denom_fu);
  block_reduce_bcast<1>(v);
  if (t == 0) blockpart[blockIdx.x] = v[0];
}

// ---------------- kernel 5: final scalar -----------------------------------
__global__ void final_kernel(const float* __restrict__ blockpart,
                             const float* __restrict__ scalars,
                             float* __restrict__ out)
{
  const int t = threadIdx.x;   // 64 threads
  float s = (t < TWO_N / 256) ? blockpart[t] : 0.f;
  #pragma unroll
  for (int off = 32; off; off >>= 1) s += __shfl_xor(s, off, 64);
  if (t == 0) out[0] = (s - 10.0f * scalars[0]) / (float)TWO_N;
}

extern "C" void kernel_launch(void* const* d_in, const int* in_sizes, int n_in,
                              void* d_out, int out_size, void* d_ws, size_t ws_size,
                              hipStream_t stream)
{
  const float* ei = (const float*)d_in[0];
  const float* ej = (const float*)d_in[1];
  const float* ek = (const float*)d_in[2];
  float* out = (float*)d_out;

  char* ws = (char*)d_ws;
  __hip_bfloat16* reps = (__hip_bfloat16*)ws;                          // 8 MB
  float* S_partial = (float*)(ws + 8u * 1024 * 1024);                  // 2 MB
  float* diagexp   = (float*)(ws + 10u * 1024 * 1024);                 // 32 KB
  float* pos_ij    = (float*)(ws + 10u * 1024 * 1024 + 32 * 1024);     // 16 KB
  float* exp_ik    = (float*)(ws + 10u * 1024 * 1024 + 48 * 1024);     // 16 KB
  float* scalars   = (float*)(ws + 10u * 1024 * 1024 + 64 * 1024);     // 8 B
  float* blockpart = (float*)(ws + 10u * 1024 * 1024 + 64 * 1024 + 256); // 128 B

  normalize_kernel<<<N_ROWS / 4, 256, 0, stream>>>(ei, ej, ek, reps, diagexp,
                                                   pos_ij, exp_ik);
  scalar_kernel<<<1, 256, 0, stream>>>(pos_ij, exp_ik, scalars);
  gemm_expsum_kernel<<<NPAIRS, 256, 0, stream>>>(reps, S_partial);
  rowlog_kernel<<<TWO_N / 256, 256, 0, stream>>>(S_partial, diagexp, scalars,
                                                 blockpart);
  final_kernel<<<1, 64, 0, stream>>>(blockpart, scalars, out);
}

// Round 11
// 70.805 us; speedup vs baseline: 2.8170x; 2.8170x over previous
//
#include <hip/hip_runtime.h>
#include <hip/hip_bf16.h>
#include <math.h>

#define N_ROWS 4096
#define D 512
#define TWO_N 8192
#define TILE 128
#define NKT 16               /* 512 / 32 K-tiles */
#define NJB 64               /* 8192 / 128 column blocks */
#define NPAIRS 2080          /* 64*65/2 upper-tri blocks */
#define INV_T 5.0f

typedef __attribute__((ext_vector_type(8))) __bf16 bf16x8;
typedef __attribute__((ext_vector_type(8))) unsigned short u16x8;
typedef __attribute__((ext_vector_type(4))) float f32x4;
#define AS1 __attribute__((address_space(1)))
#define AS3 __attribute__((address_space(3)))

// ---------------- block reduction helper (broadcasts result) ----------------
template<int K>
__device__ inline void block_reduce_bcast(float (&v)[K]) {
  __shared__ float red[4][K];
  const int t = threadIdx.x;
  #pragma unroll
  for (int off = 32; off; off >>= 1)
    #pragma unroll
    for (int i = 0; i < K; ++i) v[i] += __shfl_xor(v[i], off, 64);
  __syncthreads();
  if ((t & 63) == 0)
    #pragma unroll
    for (int i = 0; i < K; ++i) red[t >> 6][i] = v[i];
  __syncthreads();
  #pragma unroll
  for (int i = 0; i < K; ++i) v[i] = red[0][i] + red[1][i] + red[2][i] + red[3][i];
}

// ---------------- kernel 1: wave-per-row normalize (no LDS, shfl-only) -----
__global__ __launch_bounds__(256) void normalize_kernel(
    const float* __restrict__ ei_, const float* __restrict__ ej_,
    const float* __restrict__ ek_,
    __hip_bfloat16* __restrict__ reps, float* __restrict__ diagexp,
    float* __restrict__ pos_ij, float* __restrict__ exp_ik)
{
  const int t = threadIdx.x;
  const int l = t & 63;
  const int n = blockIdx.x * 4 + (t >> 6);
  const long base = (long)n * D + l * 8;

  float ai[8], aj[8], ak[8];
  #pragma unroll
  for (int h = 0; h < 2; ++h) {
    const float4 vi = *reinterpret_cast<const float4*>(ei_ + base + h * 4);
    const float4 vj = *reinterpret_cast<const float4*>(ej_ + base + h * 4);
    const float4 vk = *reinterpret_cast<const float4*>(ek_ + base + h * 4);
    ai[h*4+0]=vi.x; ai[h*4+1]=vi.y; ai[h*4+2]=vi.z; ai[h*4+3]=vi.w;
    aj[h*4+0]=vj.x; aj[h*4+1]=vj.y; aj[h*4+2]=vj.z; aj[h*4+3]=vj.w;
    ak[h*4+0]=vk.x; ak[h*4+1]=vk.y; ak[h*4+2]=vk.z; ak[h*4+3]=vk.w;
  }

  float v[5] = {0.f, 0.f, 0.f, 0.f, 0.f};
  #pragma unroll
  for (int j = 0; j < 8; ++j) {
    v[0] += ai[j] * ai[j];
    v[1] += aj[j] * aj[j];
    v[2] += ak[j] * ak[j];
    v[3] += ai[j] * aj[j];
    v[4] += ak[j] * ai[j];
  }
  #pragma unroll
  for (int off = 32; off; off >>= 1)
    #pragma unroll
    for (int i = 0; i < 5; ++i) v[i] += __shfl_xor(v[i], off, 64);

  const float ni = fmaxf(sqrtf(v[0]), 1e-12f);
  const float nj = fmaxf(sqrtf(v[1]), 1e-12f);
  const float nk = fmaxf(sqrtf(v[2]), 1e-12f);
  const float invi = 1.0f / ni, invj = 1.0f / nj;

  u16x8 ui, uj;
  float q[2] = {0.f, 0.f};
  #pragma unroll
  for (int j = 0; j < 8; ++j) {
    const __hip_bfloat16 hi = __float2bfloat16(ai[j] * invi);
    const __hip_bfloat16 hj = __float2bfloat16(aj[j] * invj);
    ui[j] = *reinterpret_cast<const unsigned short*>(&hi);
    uj[j] = *reinterpret_cast<const unsigned short*>(&hj);
    const float fi = __bfloat162float(hi), fj = __bfloat162float(hj);
    q[0] += fi * fi;
    q[1] += fj * fj;
  }
  *reinterpret_cast<u16x8*>(reps + base) = ui;
  *reinterpret_cast<u16x8*>(reps + (long)N_ROWS * D + base) = uj;

  #pragma unroll
  for (int off = 32; off; off >>= 1)
    #pragma unroll
    for (int i = 0; i < 2; ++i) q[i] += __shfl_xor(q[i], off, 64);

  if (l == 0) {
    diagexp[n]          = __expf(INV_T * q[0]);
    diagexp[N_ROWS + n] = __expf(INV_T * q[1]);
    pos_ij[n] = v[3] / (ni * nj);
    exp_ik[n] = __expf(INV_T * v[4] / (nk * ni));
  }
}

// ---------------- kernel 2: reduce the two scalars --------------------------
__global__ __launch_bounds__(256) void scalar_kernel(
    const float* __restrict__ pos_ij, const float* __restrict__ exp_ik,
    float* __restrict__ scalars)
{
  const int t = threadIdx.x;
  float v[2] = {0.f, 0.f};
  for (int i = t; i < N_ROWS; i += 256) { v[0] += pos_ij[i]; v[1] += exp_ik[i]; }
  block_reduce_bcast<2>(v);
  if (t == 0) { scalars[0] = v[0]; scalars[1] = v[1]; }
}

// ---------------- kernel 3: 128^2 BK=32 dbuf, 32KB LDS, NO reg-cap ---------
// LDS = exactly 32768 B -> LDS permits 5 blocks/CU (5*32768 = full 160 KiB).
// launch_bounds(256,4) [NOT 5 — R10 showed (256,5) caps VGPR below need and
// spills acc to scratch: VGPR 48, WRITE_SIZE 487 MB, 185 us]. Kernel needs
// ~64 VGPR naturally -> HW can still co-schedule 5 blocks (LDS-gated).
// R8 schedule: stage(k+1) issued before compute(k), one syncthreads/K-tile.
// Epilogue rowbuf/colbuf reuse staging buffers (dead after final barrier).
__device__ __forceinline__ void stage_tile(
    const __hip_bfloat16* __restrict__ reps, char* region,
    long R0, int kt, int p, int t)
{
  #pragma unroll
  for (int s = 0; s < 2; ++s) {
    const int cc = s * 256 + t;          // chunk 0..511
    const int row = cc >> 2, slot = cc & 3;
    const int sl = slot ^ ((row >> 1) & 3);
    const __hip_bfloat16* g = reps + (R0 + row) * D + kt * 32 + sl * 8;
    __builtin_amdgcn_global_load_lds((const AS1 void*)g,
        (AS3 void*)(region + p * 8192 + cc * 16), 16, 0, 0);
  }
}

__global__ __launch_bounds__(256, 4) void gemm_expsum_kernel(
    const __hip_bfloat16* __restrict__ reps, float* __restrict__ S_partial)
{
  __shared__ __align__(16) char smem[32768];
  char* Ar = smem;
  char* Br = smem + 16384;

  const int t = threadIdx.x;
  const int l = t & 63;
  const int w = t >> 6;          // wave 0..3
  const int wr = w >> 1, wc = w & 1;
  const int s4 = l >> 4;

  // XCD-aware bijective swizzle (2080 = 8*260), then triangular decode I<=J
  const int wg = (blockIdx.x & 7) * 260 + (blockIdx.x >> 3);
  int k = wg, I = 0;
  while (k >= NJB - I) { k -= NJB - I; ++I; }
  const int J = I + k;
  const long rI = (long)I * TILE;
  const long cJ = (long)J * TILE;

  // fragment byte offsets (buffer term added at read): row*64 + swizzled slot
  const int swz16 = ((s4 ^ ((l >> 1) & 3)) << 4);
  int a_off[4], b_off[4];
  #pragma unroll
  for (int mi = 0; mi < 4; ++mi)
    a_off[mi] = (wr * 64 + mi * 16 + (l & 15)) * 64 + swz16;
  #pragma unroll
  for (int ni = 0; ni < 4; ++ni)
    b_off[ni] = (wc * 64 + ni * 16 + (l & 15)) * 64 + swz16;

  f32x4 acc[4][4];
  #pragma unroll
  for (int a = 0; a < 4; ++a)
    #pragma unroll
    for (int b = 0; b < 4; ++b) { f32x4 z = {0.f, 0.f, 0.f, 0.f}; acc[a][b] = z; }

  // prologue: stage tile0 into buf0, wait (syncthreads drains vmcnt)
  stage_tile(reps, Ar, rI, 0, 0, t);
  stage_tile(reps, Br, cJ, 0, 0, t);
  __syncthreads();

  for (int kt = 0; kt < NKT; ++kt) {
    const int p = kt & 1;
    if (kt < NKT - 1) {                  // issue next tile BEFORE compute
      stage_tile(reps, Ar, rI, kt + 1, p ^ 1, t);
      stage_tile(reps, Br, cJ, kt + 1, p ^ 1, t);
    }
    bf16x8 av[4], bv[4];
    #pragma unroll
    for (int mi = 0; mi < 4; ++mi)
      av[mi] = *reinterpret_cast<const bf16x8*>(Ar + p * 8192 + a_off[mi]);
    #pragma unroll
    for (int ni = 0; ni < 4; ++ni)
      bv[ni] = *reinterpret_cast<const bf16x8*>(Br + p * 8192 + b_off[ni]);
    __builtin_amdgcn_s_setprio(1);
    #pragma unroll
    for (int mi = 0; mi < 4; ++mi)
      #pragma unroll
      for (int ni = 0; ni < 4; ++ni)
        acc[mi][ni] = __builtin_amdgcn_mfma_f32_16x16x32_bf16(
            av[mi], bv[ni], acc[mi][ni], 0, 0, 0);
    __builtin_amdgcn_s_setprio(0);
    __syncthreads();   // drains vmcnt(0): next tile landed; all done reading p
  }
  // K-loop's final barrier: all waves' ds_reads retired -> smem reusable.
  float* rowbuf = (float*)smem;              // [2][128]
  float* colbuf = (float*)(smem + 1024);     // [2][128]

  // epilogue: e = exp(5*sim); row-sums (rows of I) and col-sums (symmetry)
  float rsum[4][4], csum[4];
  #pragma unroll
  for (int mi = 0; mi < 4; ++mi)
    #pragma unroll
    for (int j = 0; j < 4; ++j) rsum[mi][j] = 0.f;
  #pragma unroll
  for (int ni = 0; ni < 4; ++ni) csum[ni] = 0.f;

  #pragma unroll
  for (int mi = 0; mi < 4; ++mi)
    #pragma unroll
    for (int ni = 0; ni < 4; ++ni)
      #pragma unroll
      for (int j = 0; j < 4; ++j) {
        const float e = __expf(INV_T * acc[mi][ni][j]);
        rsum[mi][j] += e;
        csum[ni]    += e;
      }

  #pragma unroll
  for (int mi = 0; mi < 4; ++mi) {
    #pragma unroll
    for (int off = 1; off < 16; off <<= 1)
      #pragma unroll
      for (int j = 0; j < 4; ++j) rsum[mi][j] += __shfl_xor(rsum[mi][j], off, 64);
    if ((l & 15) == 0) {
      const int rloc = wr * 64 + mi * 16 + s4 * 4;
      #pragma unroll
      for (int j = 0; j < 4; ++j) rowbuf[wc * TILE + rloc + j] = rsum[mi][j];
    }
  }
  #pragma unroll
  for (int off = 16; off < 64; off <<= 1)
    #pragma unroll
    for (int ni = 0; ni < 4; ++ni) csum[ni] += __shfl_xor(csum[ni], off, 64);
  if (l < 16) {
    #pragma unroll
    for (int ni = 0; ni < 4; ++ni)
      colbuf[wr * TILE + wc * 64 + ni * 16 + l] = csum[ni];
  }
  __syncthreads();

  if (t < TILE) {
    S_partial[(long)J * TWO_N + rI + t] = rowbuf[t] + rowbuf[TILE + t];
  } else if (I != J) {
    const int c = t - TILE;
    S_partial[(long)I * TWO_N + cJ + c] = colbuf[c] + colbuf[TILE + c];
  }
}

// ---------------- kernel 4: per-row log(denominator), block partials -------
__global__ __launch_bounds__(256) void rowlog_kernel(
    const float* __restrict__ S_partial, const float* __restrict__ diagexp,
    const float* __restrict__ scalars, float* __restrict__ blockpart)
{
  const int t = threadIdx.x;
  const int r = blockIdx.x * 256 + t;
  float s = 0.f;
  #pragma unroll 8
  for (int Jb = 0; Jb < NJB; ++Jb) s += S_partial[(long)Jb * TWO_N + r];
  const float denom_fu = 2.0f * scalars[1];
  float v[1];
  v[0] = logf(s - diagexp[r] + denom_fu);
  block_reduce_bcast<1>(v);
  if (t == 0) blockpart[blockIdx.x] = v[0];
}

// ---------------- kernel 5: final scalar -----------------------------------
__global__ void final_kernel(const float* __restrict__ blockpart,
                             const float* __restrict__ scalars,
                             float* __restrict__ out)
{
  const int t = threadIdx.x;   // 64 threads
  float s = (t < TWO_N / 256) ? blockpart[t] : 0.f;
  #pragma unroll
  for (int off = 32; off; off >>= 1) s += __shfl_xor(s, off, 64);
  if (t == 0) out[0] = (s - 10.0f * scalars[0]) / (float)TWO_N;
}

extern "C" void kernel_launch(void* const* d_in, const int* in_sizes, int n_in,
                              void* d_out, int out_size, void* d_ws, size_t ws_size,
                              hipStream_t stream)
{
  const float* ei = (const float*)d_in[0];
  const float* ej = (const float*)d_in[1];
  const float* ek = (const float*)d_in[2];
  float* out = (float*)d_out;

  char* ws = (char*)d_ws;
  __hip_bfloat16* reps = (__hip_bfloat16*)ws;                          // 8 MB
  float* S_partial = (float*)(ws + 8u * 1024 * 1024);                  // 2 MB
  float* diagexp   = (float*)(ws + 10u * 1024 * 1024);                 // 32 KB
  float* pos_ij    = (float*)(ws + 10u * 1024 * 1024 + 32 * 1024);     // 16 KB
  float* exp_ik    = (float*)(ws + 10u * 1024 * 1024 + 48 * 1024);     // 16 KB
  float* scalars   = (float*)(ws + 10u * 1024 * 1024 + 64 * 1024);     // 8 B
  float* blockpart = (float*)(ws + 10u * 1024 * 1024 + 64 * 1024 + 256); // 128 B

  normalize_kernel<<<N_ROWS / 4, 256, 0, stream>>>(ei, ej, ek, reps, diagexp,
                                                   pos_ij, exp_ik);
  scalar_kernel<<<1, 256, 0, stream>>>(pos_ij, exp_ik, scalars);
  gemm_expsum_kernel<<<NPAIRS, 256, 0, stream>>>(reps, S_partial);
  rowlog_kernel<<<TWO_N / 256, 256, 0, stream>>>(S_partial, diagexp, scalars,
                                                 blockpart);
  final_kernel<<<1, 64, 0, stream>>>(blockpart, scalars, out);
}

// Round 12
// 57.391 us; speedup vs baseline: 3.4755x; 1.2337x over previous
//
#include <hip/hip_runtime.h>
#include <hip/hip_bf16.h>
#include <math.h>

#define N_ROWS 4096
#define D 512
#define TWO_N 8192
#define TILE 128
#define NKT 4                /* 512 / 128 K-tiles */
#define NJB 64               /* 8192 / 128 column blocks */
#define NPAIRS 2080          /* 64*65/2 upper-tri blocks */
#define INV_T 5.0f

typedef __attribute__((ext_vector_type(4))) int i32x4;
typedef __attribute__((ext_vector_type(8))) int i32x8;
typedef __attribute__((ext_vector_type(2))) float f32x2;
typedef __attribute__((ext_vector_type(4))) float f32x4;
#define AS1 __attribute__((address_space(1)))
#define AS3 __attribute__((address_space(3)))

// ---------------- block reduction helper (broadcasts result) ----------------
template<int K>
__device__ inline void block_reduce_bcast(float (&v)[K]) {
  __shared__ float red[4][K];
  const int t = threadIdx.x;
  #pragma unroll
  for (int off = 32; off; off >>= 1)
    #pragma unroll
    for (int i = 0; i < K; ++i) v[i] += __shfl_xor(v[i], off, 64);
  __syncthreads();
  if ((t & 63) == 0)
    #pragma unroll
    for (int i = 0; i < K; ++i) red[t >> 6][i] = v[i];
  __syncthreads();
  #pragma unroll
  for (int i = 0; i < K; ++i) v[i] = red[0][i] + red[1][i] + red[2][i] + red[3][i];
}

// ---------------- kernel 1: wave-per-row normalize -> fp8 e4m3 reps --------
__global__ __launch_bounds__(256) void normalize_kernel(
    const float* __restrict__ ei_, const float* __restrict__ ej_,
    const float* __restrict__ ek_,
    unsigned char* __restrict__ rep8, float* __restrict__ diagexp,
    float* __restrict__ pos_ij, float* __restrict__ exp_ik)
{
  const int t = threadIdx.x;
  const int l = t & 63;
  const int n = blockIdx.x * 4 + (t >> 6);
  const long base = (long)n * D + l * 8;

  float ai[8], aj[8], ak[8];
  #pragma unroll
  for (int h = 0; h < 2; ++h) {
    const float4 vi = *reinterpret_cast<const float4*>(ei_ + base + h * 4);
    const float4 vj = *reinterpret_cast<const float4*>(ej_ + base + h * 4);
    const float4 vk = *reinterpret_cast<const float4*>(ek_ + base + h * 4);
    ai[h*4+0]=vi.x; ai[h*4+1]=vi.y; ai[h*4+2]=vi.z; ai[h*4+3]=vi.w;
    aj[h*4+0]=vj.x; aj[h*4+1]=vj.y; aj[h*4+2]=vj.z; aj[h*4+3]=vj.w;
    ak[h*4+0]=vk.x; ak[h*4+1]=vk.y; ak[h*4+2]=vk.z; ak[h*4+3]=vk.w;
  }

  float v[5] = {0.f, 0.f, 0.f, 0.f, 0.f};
  #pragma unroll
  for (int j = 0; j < 8; ++j) {
    v[0] += ai[j] * ai[j];
    v[1] += aj[j] * aj[j];
    v[2] += ak[j] * ak[j];
    v[3] += ai[j] * aj[j];
    v[4] += ak[j] * ai[j];
  }
  #pragma unroll
  for (int off = 32; off; off >>= 1)
    #pragma unroll
    for (int i = 0; i < 5; ++i) v[i] += __shfl_xor(v[i], off, 64);

  const float ni = fmaxf(sqrtf(v[0]), 1e-12f);
  const float nj = fmaxf(sqrtf(v[1]), 1e-12f);
  const float nk = fmaxf(sqrtf(v[2]), 1e-12f);
  const float invi = 1.0f / ni, invj = 1.0f / nj;

  // quantize normalized rows to fp8 e4m3 (OCP, HW cvt), pack 8/lane
  float zi[8], zj[8];
  #pragma unroll
  for (int j = 0; j < 8; ++j) { zi[j] = ai[j] * invi; zj[j] = aj[j] * invj; }
  int wi0 = __builtin_amdgcn_cvt_pk_fp8_f32(zi[0], zi[1], 0, false);
  wi0     = __builtin_amdgcn_cvt_pk_fp8_f32(zi[2], zi[3], wi0, true);
  int wi1 = __builtin_amdgcn_cvt_pk_fp8_f32(zi[4], zi[5], 0, false);
  wi1     = __builtin_amdgcn_cvt_pk_fp8_f32(zi[6], zi[7], wi1, true);
  int wj0 = __builtin_amdgcn_cvt_pk_fp8_f32(zj[0], zj[1], 0, false);
  wj0     = __builtin_amdgcn_cvt_pk_fp8_f32(zj[2], zj[3], wj0, true);
  int wj1 = __builtin_amdgcn_cvt_pk_fp8_f32(zj[4], zj[5], 0, false);
  wj1     = __builtin_amdgcn_cvt_pk_fp8_f32(zj[6], zj[7], wj1, true);
  int2 pi; pi.x = wi0; pi.y = wi1;
  int2 pj; pj.x = wj0; pj.y = wj1;
  *reinterpret_cast<int2*>(rep8 + base) = pi;
  *reinterpret_cast<int2*>(rep8 + (long)N_ROWS * D + base) = pj;

  // diag = sum of squares of the DEQUANTIZED values (matches MFMA diagonal)
  float q[2] = {0.f, 0.f};
  #pragma unroll
  for (int h = 0; h < 2; ++h) {
    const int wi = h ? wi1 : wi0, wj = h ? wj1 : wj0;
    const f32x2 d0 = __builtin_amdgcn_cvt_pk_f32_fp8(wi, false);
    const f32x2 d1 = __builtin_amdgcn_cvt_pk_f32_fp8(wi, true);
    const f32x2 e0 = __builtin_amdgcn_cvt_pk_f32_fp8(wj, false);
    const f32x2 e1 = __builtin_amdgcn_cvt_pk_f32_fp8(wj, true);
    q[0] += d0.x*d0.x + d0.y*d0.y + d1.x*d1.x + d1.y*d1.y;
    q[1] += e0.x*e0.x + e0.y*e0.y + e1.x*e1.x + e1.y*e1.y;
  }
  #pragma unroll
  for (int off = 32; off; off >>= 1)
    #pragma unroll
    for (int i = 0; i < 2; ++i) q[i] += __shfl_xor(q[i], off, 64);

  if (l == 0) {
    diagexp[n]          = __expf(INV_T * q[0]);
    diagexp[N_ROWS + n] = __expf(INV_T * q[1]);
    pos_ij[n] = v[3] / (ni * nj);
    exp_ik[n] = __expf(INV_T * v[4] / (nk * ni));
  }
}

// ---------------- kernel 2: reduce the two scalars --------------------------
__global__ __launch_bounds__(256) void scalar_kernel(
    const float* __restrict__ pos_ij, const float* __restrict__ exp_ik,
    float* __restrict__ scalars)
{
  const int t = threadIdx.x;
  float v[2] = {0.f, 0.f};
  for (int i = t; i < N_ROWS; i += 256) { v[0] += pos_ij[i]; v[1] += exp_ik[i]; }
  block_reduce_bcast<2>(v);
  if (t == 0) { scalars[0] = v[0]; scalars[1] = v[1]; }
}

// ---------------- kernel 3: 128^2 MX-fp8 K=128 GEMM + exp + sums -----------
// mfma_scale_f32_16x16x128_f8f6f4, unit scales (0x7F7F7F7F -> 2^0 any opsel).
// LDS 32KB: A[128x128 fp8]=16K + B=16K, single-buffered, 2-barrier, NKT=4.
// Row = 128B = 8 slots of 16B; swizzle slot^(row&7) (2 lanes/bank = free);
// inverse swizzle on global source; A and B staged IDENTICALLY so any k-
// permutation in the operand layout cancels (C=Z Z^T both operands from reps).
__device__ __forceinline__ void stage128(
    const unsigned char* __restrict__ rep8, char* region,
    long R0, int kt, int t)
{
  #pragma unroll
  for (int s = 0; s < 4; ++s) {
    const int cc = s * 256 + t;          // chunk 0..1023
    const int row = cc >> 3, slot = cc & 7;
    const int sg = slot ^ (row & 7);     // inverse-swizzled source slot
    const unsigned char* g = rep8 + (R0 + row) * D + kt * 128 + sg * 16;
    __builtin_amdgcn_global_load_lds((const AS1 void*)g,
        (AS3 void*)(region + cc * 16), 16, 0, 0);
  }
}

__global__ __launch_bounds__(256, 3) void gemm_expsum_kernel(
    const unsigned char* __restrict__ rep8, float* __restrict__ S_partial)
{
  __shared__ __align__(16) char smem[32768];
  char* Ar = smem;
  char* Br = smem + 16384;

  const int t = threadIdx.x;
  const int l = t & 63;
  const int w = t >> 6;          // wave 0..3
  const int wr = w >> 1, wc = w & 1;
  const int s4 = l >> 4;         // k-group g = 0..3

  // XCD-aware bijective swizzle (2080 = 8*260), then triangular decode I<=J
  const int wg = (blockIdx.x & 7) * 260 + (blockIdx.x >> 3);
  int k = wg, I = 0;
  while (k >= NJB - I) { k -= NJB - I; ++I; }
  const int J = I + k;
  const long rI = (long)I * TILE;
  const long cJ = (long)J * TILE;

  // fragment byte offsets: row*128 + ((2g+h)^(row&7))*16, h = 0,1
  int a_off[4][2], b_off[4][2];
  #pragma unroll
  for (int mi = 0; mi < 4; ++mi) {
    const int r = wr * 64 + mi * 16 + (l & 15);
    #pragma unroll
    for (int h = 0; h < 2; ++h)
      a_off[mi][h] = r * 128 + (((s4 * 2 + h) ^ (r & 7)) * 16);
  }
  #pragma unroll
  for (int ni = 0; ni < 4; ++ni) {
    const int r = wc * 64 + ni * 16 + (l & 15);
    #pragma unroll
    for (int h = 0; h < 2; ++h)
      b_off[ni][h] = r * 128 + (((s4 * 2 + h) ^ (r & 7)) * 16);
  }

  f32x4 acc[4][4];
  #pragma unroll
  for (int a = 0; a < 4; ++a)
    #pragma unroll
    for (int b = 0; b < 4; ++b) { f32x4 z = {0.f, 0.f, 0.f, 0.f}; acc[a][b] = z; }

  for (int kt = 0; kt < NKT; ++kt) {
    if (kt) __syncthreads();             // everyone done reading prev tile
    stage128(rep8, Ar, rI, kt, t);
    stage128(rep8, Br, cJ, kt, t);
    __syncthreads();                     // drains vmcnt(0): tile landed

    i32x8 bf[4];
    #pragma unroll
    for (int ni = 0; ni < 4; ++ni) {
      const i32x4 lo = *reinterpret_cast<const i32x4*>(Br + b_off[ni][0]);
      const i32x4 hi = *reinterpret_cast<const i32x4*>(Br + b_off[ni][1]);
      bf[ni] = __builtin_shufflevector(lo, hi, 0, 1, 2, 3, 4, 5, 6, 7);
    }
    __builtin_amdgcn_s_setprio(1);
    #pragma unroll
    for (int mi = 0; mi < 4; ++mi) {
      const i32x4 lo = *reinterpret_cast<const i32x4*>(Ar + a_off[mi][0]);
      const i32x4 hi = *reinterpret_cast<const i32x4*>(Ar + a_off[mi][1]);
      const i32x8 af = __builtin_shufflevector(lo, hi, 0, 1, 2, 3, 4, 5, 6, 7);
      #pragma unroll
      for (int ni = 0; ni < 4; ++ni)
        acc[mi][ni] = __builtin_amdgcn_mfma_scale_f32_16x16x128_f8f6f4(
            af, bf[ni], acc[mi][ni], 0 /*A fmt fp8*/, 0 /*B fmt fp8*/,
            0, 0x7F7F7F7F, 0, 0x7F7F7F7F);
    }
    __builtin_amdgcn_s_setprio(0);
  }
  __syncthreads();                       // all ds_reads retired: smem reusable
  float* rowbuf = (float*)smem;          // [2][128]
  float* colbuf = (float*)(smem + 1024); // [2][128]

  // epilogue: e = exp(5*sim); row-sums (rows of I) and col-sums (symmetry)
  // C/D layout shape-determined (m127/m128): col=l&15, row=(l>>4)*4+j
  float rsum[4][4], csum[4];
  #pragma unroll
  for (int mi = 0; mi < 4; ++mi)
    #pragma unroll
    for (int j = 0; j < 4; ++j) rsum[mi][j] = 0.f;
  #pragma unroll
  for (int ni = 0; ni < 4; ++ni) csum[ni] = 0.f;

  #pragma unroll
  for (int mi = 0; mi < 4; ++mi)
    #pragma unroll
    for (int ni = 0; ni < 4; ++ni)
      #pragma unroll
      for (int j = 0; j < 4; ++j) {
        const float e = __expf(INV_T * acc[mi][ni][j]);
        rsum[mi][j] += e;
        csum[ni]    += e;
      }

  #pragma unroll
  for (int mi = 0; mi < 4; ++mi) {
    #pragma unroll
    for (int off = 1; off < 16; off <<= 1)
      #pragma unroll
      for (int j = 0; j < 4; ++j) rsum[mi][j] += __shfl_xor(rsum[mi][j], off, 64);
    if ((l & 15) == 0) {
      const int rloc = wr * 64 + mi * 16 + s4 * 4;
      #pragma unroll
      for (int j = 0; j < 4; ++j) rowbuf[wc * TILE + rloc + j] = rsum[mi][j];
    }
  }
  #pragma unroll
  for (int off = 16; off < 64; off <<= 1)
    #pragma unroll
    for (int ni = 0; ni < 4; ++ni) csum[ni] += __shfl_xor(csum[ni], off, 64);
  if (l < 16) {
    #pragma unroll
    for (int ni = 0; ni < 4; ++ni)
      colbuf[wr * TILE + wc * 64 + ni * 16 + l] = csum[ni];
  }
  __syncthreads();

  if (t < TILE) {
    S_partial[(long)J * TWO_N + rI + t] = rowbuf[t] + rowbuf[TILE + t];
  } else if (I != J) {
    const int c = t - TILE;
    S_partial[(long)I * TWO_N + cJ + c] = colbuf[c] + colbuf[TILE + c];
  }
}

// ---------------- kernel 4: per-row log(denominator), block partials -------
__global__ __launch_bounds__(256) void rowlog_kernel(
    const float* __restrict__ S_partial, const float* __restrict__ diagexp,
    const float* __restrict__ scalars, float* __restrict__ blockpart)
{
  const int t = threadIdx.x;
  const int r = blockIdx.x * 256 + t;
  float s = 0.f;
  #pragma unroll 8
  for (int Jb = 0; Jb < NJB; ++Jb) s += S_partial[(long)Jb * TWO_N + r];
  const float denom_fu = 2.0f * scalars[1];
  float v[1];
  v[0] = logf(s - diagexp[r] + denom_fu);
  block_reduce_bcast<1>(v);
  if (t == 0) blockpart[blockIdx.x] = v[0];
}

// ---------------- kernel 5: final scalar -----------------------------------
__global__ void final_kernel(const float* __restrict__ blockpart,
                             const float* __restrict__ scalars,
                             float* __restrict__ out)
{
  const int t = threadIdx.x;   // 64 threads
  float s = (t < TWO_N / 256) ? blockpart[t] : 0.f;
  #pragma unroll
  for (int off = 32; off; off >>= 1) s += __shfl_xor(s, off, 64);
  if (t == 0) out[0] = (s - 10.0f * scalars[0]) / (float)TWO_N;
}

extern "C" void kernel_launch(void* const* d_in, const int* in_sizes, int n_in,
                              void* d_out, int out_size, void* d_ws, size_t ws_size,
                              hipStream_t stream)
{
  const float* ei = (const float*)d_in[0];
  const float* ej = (const float*)d_in[1];
  const float* ek = (const float*)d_in[2];
  float* out = (float*)d_out;

  char* ws = (char*)d_ws;
  unsigned char* rep8 = (unsigned char*)ws;                            // 4 MB
  float* S_partial = (float*)(ws + 4u * 1024 * 1024);                  // 2 MB
  float* diagexp   = (float*)(ws + 6u * 1024 * 1024);                  // 32 KB
  float* pos_ij    = (float*)(ws + 6u * 1024 * 1024 + 32 * 1024);      // 16 KB
  float* exp_ik    = (float*)(ws + 6u * 1024 * 1024 + 48 * 1024);      // 16 KB
  float* scalars   = (float*)(ws + 6u * 1024 * 1024 + 64 * 1024);      // 8 B
  float* blockpart = (float*)(ws + 6u * 1024 * 1024 + 64 * 1024 + 256); // 128 B

  normalize_kernel<<<N_ROWS / 4, 256, 0, stream>>>(ei, ej, ek, rep8, diagexp,
                                                   pos_ij, exp_ik);
  scalar_kernel<<<1, 256, 0, stream>>>(pos_ij, exp_ik, scalars);
  gemm_expsum_kernel<<<NPAIRS, 256, 0, stream>>>(rep8, S_partial);
  rowlog_kernel<<<TWO_N / 256, 256, 0, stream>>>(S_partial, diagexp, scalars,
                                                 blockpart);
  final_kernel<<<1, 64, 0, stream>>>(blockpart, scalars, out);
}

// Round 13
// 57.025 us; speedup vs baseline: 3.4978x; 1.0064x over previous
//
#include <hip/hip_runtime.h>
#include <hip/hip_bf16.h>
#include <math.h>

#define N_ROWS 4096
#define D 512
#define TWO_N 8192
#define TILE 128
#define NKT 4                /* 512 / 128 K-tiles */
#define NJB 64               /* 8192 / 128 column blocks */
#define NPAIRS 2080          /* 64*65/2 upper-tri blocks */
#define INV_T 5.0f

typedef __attribute__((ext_vector_type(4))) int i32x4;
typedef __attribute__((ext_vector_type(8))) int i32x8;
typedef __attribute__((ext_vector_type(2))) float f32x2;
typedef __attribute__((ext_vector_type(4))) float f32x4;
#define AS1 __attribute__((address_space(1)))
#define AS3 __attribute__((address_space(3)))

// ---------------- block reduction helper (broadcasts result) ----------------
template<int K>
__device__ inline void block_reduce_bcast(float (&v)[K]) {
  __shared__ float red[4][K];
  const int t = threadIdx.x;
  #pragma unroll
  for (int off = 32; off; off >>= 1)
    #pragma unroll
    for (int i = 0; i < K; ++i) v[i] += __shfl_xor(v[i], off, 64);
  __syncthreads();
  if ((t & 63) == 0)
    #pragma unroll
    for (int i = 0; i < K; ++i) red[t >> 6][i] = v[i];
  __syncthreads();
  #pragma unroll
  for (int i = 0; i < K; ++i) v[i] = red[0][i] + red[1][i] + red[2][i] + red[3][i];
}

// ---------------- kernel 1: wave-per-row normalize -> fp8 e4m3 reps --------
__global__ __launch_bounds__(256) void normalize_kernel(
    const float* __restrict__ ei_, const float* __restrict__ ej_,
    const float* __restrict__ ek_,
    unsigned char* __restrict__ rep8, float* __restrict__ diagexp,
    float* __restrict__ pos_ij, float* __restrict__ exp_ik)
{
  const int t = threadIdx.x;
  const int l = t & 63;
  const int n = blockIdx.x * 4 + (t >> 6);
  const long base = (long)n * D + l * 8;

  float ai[8], aj[8], ak[8];
  #pragma unroll
  for (int h = 0; h < 2; ++h) {
    const float4 vi = *reinterpret_cast<const float4*>(ei_ + base + h * 4);
    const float4 vj = *reinterpret_cast<const float4*>(ej_ + base + h * 4);
    const float4 vk = *reinterpret_cast<const float4*>(ek_ + base + h * 4);
    ai[h*4+0]=vi.x; ai[h*4+1]=vi.y; ai[h*4+2]=vi.z; ai[h*4+3]=vi.w;
    aj[h*4+0]=vj.x; aj[h*4+1]=vj.y; aj[h*4+2]=vj.z; aj[h*4+3]=vj.w;
    ak[h*4+0]=vk.x; ak[h*4+1]=vk.y; ak[h*4+2]=vk.z; ak[h*4+3]=vk.w;
  }

  float v[5] = {0.f, 0.f, 0.f, 0.f, 0.f};
  #pragma unroll
  for (int j = 0; j < 8; ++j) {
    v[0] += ai[j] * ai[j];
    v[1] += aj[j] * aj[j];
    v[2] += ak[j] * ak[j];
    v[3] += ai[j] * aj[j];
    v[4] += ak[j] * ai[j];
  }
  #pragma unroll
  for (int off = 32; off; off >>= 1)
    #pragma unroll
    for (int i = 0; i < 5; ++i) v[i] += __shfl_xor(v[i], off, 64);

  const float ni = fmaxf(sqrtf(v[0]), 1e-12f);
  const float nj = fmaxf(sqrtf(v[1]), 1e-12f);
  const float nk = fmaxf(sqrtf(v[2]), 1e-12f);
  const float invi = 1.0f / ni, invj = 1.0f / nj;

  // quantize normalized rows to fp8 e4m3 (OCP, HW cvt), pack 8/lane
  float zi[8], zj[8];
  #pragma unroll
  for (int j = 0; j < 8; ++j) { zi[j] = ai[j] * invi; zj[j] = aj[j] * invj; }
  int wi0 = __builtin_amdgcn_cvt_pk_fp8_f32(zi[0], zi[1], 0, false);
  wi0     = __builtin_amdgcn_cvt_pk_fp8_f32(zi[2], zi[3], wi0, true);
  int wi1 = __builtin_amdgcn_cvt_pk_fp8_f32(zi[4], zi[5], 0, false);
  wi1     = __builtin_amdgcn_cvt_pk_fp8_f32(zi[6], zi[7], wi1, true);
  int wj0 = __builtin_amdgcn_cvt_pk_fp8_f32(zj[0], zj[1], 0, false);
  wj0     = __builtin_amdgcn_cvt_pk_fp8_f32(zj[2], zj[3], wj0, true);
  int wj1 = __builtin_amdgcn_cvt_pk_fp8_f32(zj[4], zj[5], 0, false);
  wj1     = __builtin_amdgcn_cvt_pk_fp8_f32(zj[6], zj[7], wj1, true);
  int2 pi; pi.x = wi0; pi.y = wi1;
  int2 pj; pj.x = wj0; pj.y = wj1;
  *reinterpret_cast<int2*>(rep8 + base) = pi;
  *reinterpret_cast<int2*>(rep8 + (long)N_ROWS * D + base) = pj;

  // diag = sum of squares of the DEQUANTIZED values (matches MFMA diagonal)
  float q[2] = {0.f, 0.f};
  #pragma unroll
  for (int h = 0; h < 2; ++h) {
    const int wi = h ? wi1 : wi0, wj = h ? wj1 : wj0;
    const f32x2 d0 = __builtin_amdgcn_cvt_pk_f32_fp8(wi, false);
    const f32x2 d1 = __builtin_amdgcn_cvt_pk_f32_fp8(wi, true);
    const f32x2 e0 = __builtin_amdgcn_cvt_pk_f32_fp8(wj, false);
    const f32x2 e1 = __builtin_amdgcn_cvt_pk_f32_fp8(wj, true);
    q[0] += d0.x*d0.x + d0.y*d0.y + d1.x*d1.x + d1.y*d1.y;
    q[1] += e0.x*e0.x + e0.y*e0.y + e1.x*e1.x + e1.y*e1.y;
  }
  #pragma unroll
  for (int off = 32; off; off >>= 1)
    #pragma unroll
    for (int i = 0; i < 2; ++i) q[i] += __shfl_xor(q[i], off, 64);

  if (l == 0) {
    diagexp[n]          = __expf(INV_T * q[0]);
    diagexp[N_ROWS + n] = __expf(INV_T * q[1]);
    pos_ij[n] = v[3] / (ni * nj);
    exp_ik[n] = __expf(INV_T * v[4] / (nk * ni));
  }
}

// ---------------- kernel 2: reduce the two scalars --------------------------
__global__ __launch_bounds__(256) void scalar_kernel(
    const float* __restrict__ pos_ij, const float* __restrict__ exp_ik,
    float* __restrict__ scalars)
{
  const int t = threadIdx.x;
  float v[2] = {0.f, 0.f};
  for (int i = t; i < N_ROWS; i += 256) { v[0] += pos_ij[i]; v[1] += exp_ik[i]; }
  block_reduce_bcast<2>(v);
  if (t == 0) { scalars[0] = v[0]; scalars[1] = v[1]; }
}

// ---------------- kernel 3: 128^2 MX-fp8 K=128, dbuf stage-ahead -----------
// R12 datapath (mfma_scale 16x16x128, unit scales) + R8/R11 proven schedule:
// stage T(k+1) into buffer p^1 BEFORE computing T(k); ONE syncthreads per
// K-tile (its vmcnt drain lands after ~550cyc of MFMA -> hidden). LDS 64KB
// (2 x [A16K|B16K]) -> 2 blocks/CU. Hazard: barrier ending iter k-1 retires
// all reads of buf p^1 before iter k overwrites it (R8 ledger).
// Row = 128B = 8 slots of 16B; swizzle slot^(row&7); inverse on source.
__device__ __forceinline__ void stage128(
    const unsigned char* __restrict__ rep8, char* region,
    long R0, int kt, int t)
{
  #pragma unroll
  for (int s = 0; s < 4; ++s) {
    const int cc = s * 256 + t;          // chunk 0..1023
    const int row = cc >> 3, slot = cc & 7;
    const int sg = slot ^ (row & 7);     // inverse-swizzled source slot
    const unsigned char* g = rep8 + (R0 + row) * D + kt * 128 + sg * 16;
    __builtin_amdgcn_global_load_lds((const AS1 void*)g,
        (AS3 void*)(region + cc * 16), 16, 0, 0);
  }
}

__global__ __launch_bounds__(256, 2) void gemm_expsum_kernel(
    const unsigned char* __restrict__ rep8, float* __restrict__ S_partial)
{
  __shared__ __align__(16) char smem[65536];   // [p][A 16K | B 16K]

  const int t = threadIdx.x;
  const int l = t & 63;
  const int w = t >> 6;          // wave 0..3
  const int wr = w >> 1, wc = w & 1;
  const int s4 = l >> 4;         // k-group g = 0..3

  // XCD-aware bijective swizzle (2080 = 8*260), then triangular decode I<=J
  const int wg = (blockIdx.x & 7) * 260 + (blockIdx.x >> 3);
  int k = wg, I = 0;
  while (k >= NJB - I) { k -= NJB - I; ++I; }
  const int J = I + k;
  const long rI = (long)I * TILE;
  const long cJ = (long)J * TILE;

  // fragment byte offsets within a buffer: row*128 + ((2g+h)^(row&7))*16
  int a_off[4][2], b_off[4][2];
  #pragma unroll
  for (int mi = 0; mi < 4; ++mi) {
    const int r = wr * 64 + mi * 16 + (l & 15);
    #pragma unroll
    for (int h = 0; h < 2; ++h)
      a_off[mi][h] = r * 128 + (((s4 * 2 + h) ^ (r & 7)) * 16);
  }
  #pragma unroll
  for (int ni = 0; ni < 4; ++ni) {
    const int r = wc * 64 + ni * 16 + (l & 15);
    #pragma unroll
    for (int h = 0; h < 2; ++h)
      b_off[ni][h] = 16384 + r * 128 + (((s4 * 2 + h) ^ (r & 7)) * 16);
  }

  f32x4 acc[4][4];
  #pragma unroll
  for (int a = 0; a < 4; ++a)
    #pragma unroll
    for (int b = 0; b < 4; ++b) { f32x4 z = {0.f, 0.f, 0.f, 0.f}; acc[a][b] = z; }

  // prologue: stage T0 into buf0; syncthreads drains vmcnt
  stage128(rep8, smem, rI, 0, t);
  stage128(rep8, smem + 16384, cJ, 0, t);
  __syncthreads();

  for (int kt = 0; kt < NKT; ++kt) {
    const int p = kt & 1;
    char* cur = smem + p * 32768;
    if (kt < NKT - 1) {                  // issue next tile BEFORE compute
      char* nxt = smem + (p ^ 1) * 32768;
      stage128(rep8, nxt, rI, kt + 1, t);
      stage128(rep8, nxt + 16384, cJ, kt + 1, t);
    }
    i32x8 bf[4];
    #pragma unroll
    for (int ni = 0; ni < 4; ++ni) {
      const i32x4 lo = *reinterpret_cast<const i32x4*>(cur + b_off[ni][0]);
      const i32x4 hi = *reinterpret_cast<const i32x4*>(cur + b_off[ni][1]);
      bf[ni] = __builtin_shufflevector(lo, hi, 0, 1, 2, 3, 4, 5, 6, 7);
    }
    __builtin_amdgcn_s_setprio(1);
    #pragma unroll
    for (int mi = 0; mi < 4; ++mi) {
      const i32x4 lo = *reinterpret_cast<const i32x4*>(cur + a_off[mi][0]);
      const i32x4 hi = *reinterpret_cast<const i32x4*>(cur + a_off[mi][1]);
      const i32x8 af = __builtin_shufflevector(lo, hi, 0, 1, 2, 3, 4, 5, 6, 7);
      #pragma unroll
      for (int ni = 0; ni < 4; ++ni)
        acc[mi][ni] = __builtin_amdgcn_mfma_scale_f32_16x16x128_f8f6f4(
            af, bf[ni], acc[mi][ni], 0 /*A fmt fp8*/, 0 /*B fmt fp8*/,
            0, 0x7F7F7F7F, 0, 0x7F7F7F7F);
    }
    __builtin_amdgcn_s_setprio(0);
    __syncthreads();   // drains vmcnt(0): T(k+1) landed; all reads of p done
  }
  float* rowbuf = (float*)smem;          // [2][128] (smem dead after barrier)
  float* colbuf = (float*)(smem + 1024); // [2][128]

  // epilogue: e = exp(5*sim); row-sums (rows of I) and col-sums (symmetry)
  // C/D layout shape-determined (m127/m128): col=l&15, row=(l>>4)*4+j
  float rsum[4][4], csum[4];
  #pragma unroll
  for (int mi = 0; mi < 4; ++mi)
    #pragma unroll
    for (int j = 0; j < 4; ++j) rsum[mi][j] = 0.f;
  #pragma unroll
  for (int ni = 0; ni < 4; ++ni) csum[ni] = 0.f;

  #pragma unroll
  for (int mi = 0; mi < 4; ++mi)
    #pragma unroll
    for (int ni = 0; ni < 4; ++ni)
      #pragma unroll
      for (int j = 0; j < 4; ++j) {
        const float e = __expf(INV_T * acc[mi][ni][j]);
        rsum[mi][j] += e;
        csum[ni]    += e;
      }

  #pragma unroll
  for (int mi = 0; mi < 4; ++mi) {
    #pragma unroll
    for (int off = 1; off < 16; off <<= 1)
      #pragma unroll
      for (int j = 0; j < 4; ++j) rsum[mi][j] += __shfl_xor(rsum[mi][j], off, 64);
    if ((l & 15) == 0) {
      const int rloc = wr * 64 + mi * 16 + s4 * 4;
      #pragma unroll
      for (int j = 0; j < 4; ++j) rowbuf[wc * TILE + rloc + j] = rsum[mi][j];
    }
  }
  #pragma unroll
  for (int off = 16; off < 64; off <<= 1)
    #pragma unroll
    for (int ni = 0; ni < 4; ++ni) csum[ni] += __shfl_xor(csum[ni], off, 64);
  if (l < 16) {
    #pragma unroll
    for (int ni = 0; ni < 4; ++ni)
      colbuf[wr * TILE + wc * 64 + ni * 16 + l] = csum[ni];
  }
  __syncthreads();

  if (t < TILE) {
    S_partial[(long)J * TWO_N + rI + t] = rowbuf[t] + rowbuf[TILE + t];
  } else if (I != J) {
    const int c = t - TILE;
    S_partial[(long)I * TWO_N + cJ + c] = colbuf[c] + colbuf[TILE + c];
  }
}

// ---------------- kernel 4: per-row log(denominator), block partials -------
__global__ __launch_bounds__(256) void rowlog_kernel(
    const float* __restrict__ S_partial, const float* __restrict__ diagexp,
    const float* __restrict__ scalars, float* __restrict__ blockpart)
{
  const int t = threadIdx.x;
  const int r = blockIdx.x * 256 + t;
  float s = 0.f;
  #pragma unroll 8
  for (int Jb = 0; Jb < NJB; ++Jb) s += S_partial[(long)Jb * TWO_N + r];
  const float denom_fu = 2.0f * scalars[1];
  float v[1];
  v[0] = logf(s - diagexp[r] + denom_fu);
  block_reduce_bcast<1>(v);
  if (t == 0) blockpart[blockIdx.x] = v[0];
}

// ---------------- kernel 5: final scalar -----------------------------------
__global__ void final_kernel(const float* __restrict__ blockpart,
                             const float* __restrict__ scalars,
                             float* __restrict__ out)
{
  const int t = threadIdx.x;   // 64 threads
  float s = (t < TWO_N / 256) ? blockpart[t] : 0.f;
  #pragma unroll
  for (int off = 32; off; off >>= 1) s += __shfl_xor(s, off, 64);
  if (t == 0) out[0] = (s - 10.0f * scalars[0]) / (float)TWO_N;
}

extern "C" void kernel_launch(void* const* d_in, const int* in_sizes, int n_in,
                              void* d_out, int out_size, void* d_ws, size_t ws_size,
                              hipStream_t stream)
{
  const float* ei = (const float*)d_in[0];
  const float* ej = (const float*)d_in[1];
  const float* ek = (const float*)d_in[2];
  float* out = (float*)d_out;

  char* ws = (char*)d_ws;
  unsigned char* rep8 = (unsigned char*)ws;                            // 4 MB
  float* S_partial = (float*)(ws + 4u * 1024 * 1024);                  // 2 MB
  float* diagexp   = (float*)(ws + 6u * 1024 * 1024);                  // 32 KB
  float* pos_ij    = (float*)(ws + 6u * 1024 * 1024 + 32 * 1024);      // 16 KB
  float* exp_ik    = (float*)(ws + 6u * 1024 * 1024 + 48 * 1024);      // 16 KB
  float* scalars   = (float*)(ws + 6u * 1024 * 1024 + 64 * 1024);      // 8 B
  float* blockpart = (float*)(ws + 6u * 1024 * 1024 + 64 * 1024 + 256); // 128 B

  normalize_kernel<<<N_ROWS / 4, 256, 0, stream>>>(ei, ej, ek, rep8, diagexp,
                                                   pos_ij, exp_ik);
  scalar_kernel<<<1, 256, 0, stream>>>(pos_ij, exp_ik, scalars);
  gemm_expsum_kernel<<<NPAIRS, 256, 0, stream>>>(rep8, S_partial);
  rowlog_kernel<<<TWO_N / 256, 256, 0, stream>>>(S_partial, diagexp, scalars,
                                                 blockpart);
  final_kernel<<<1, 64, 0, stream>>>(blockpart, scalars, out);
}